// Round 1
// 736.019 us; speedup vs baseline: 1.1151x; 1.1151x over previous
//
#include <hip/hip_runtime.h>
#include <math.h>

// Problem constants
#define HID   768
#define DIMD  192
#define NSIG  15
#define BB    32
#define SS    4096
#define SC    128                 // tokens per fused block
#define NCHUNK (SS / SC)          // 32
#define HC2   16                  // h-cols staged per stage (per quarter)
#define NST   (192 / HC2)         // 12 stage iterations
#define INV_SCALE 0.07216878364870322f   // 1/sqrt(192)
#define LOG_S     8.31776616671934f      // ln(4096)

// Workspace layout (floats) — unchanged from previous version
#define WS_QK   ((size_t)0)                      // [15][768] scaled Q
#define WS_QB   (WS_QK + NSIG * HID)             // [15] scaled bias dot
#define WS_ST   (WS_QB + 16)                     // [B][32][15][3] m,l,pa partials
#define WS_CTXP (WS_ST + (size_t)BB * NCHUNK * NSIG * 3)  // [B][32][15][768]

// ---------------- Kernel A: Qk[n][h] = (q[n,:]·Wk[h,:])/sqrt(d), qb[n] = (q[n]·bk)/sqrt(d)
__global__ __launch_bounds__(256) void k_qk(const float* __restrict__ q,
                                            const float* __restrict__ Wk,
                                            const float* __restrict__ bk,
                                            float* __restrict__ ws) {
  int idx = blockIdx.x * 256 + threadIdx.x;
  if (idx < NSIG * HID) {
    int n = idx / HID, h = idx - n * HID;
    const float* qr = q + n * DIMD;
    const float* wr = Wk + h * DIMD;
    float s = 0.f;
    #pragma unroll 4
    for (int d = 0; d < DIMD; ++d) s = fmaf(qr[d], wr[d], s);
    ws[WS_QK + (size_t)n * HID + h] = s * INV_SCALE;
  }
  if (idx < NSIG) {
    const float* qr = q + idx * DIMD;
    float s = 0.f;
    for (int d = 0; d < DIMD; ++d) s = fmaf(qr[d], bk[d], s);
    ws[WS_QB + idx] = s * INV_SCALE;
  }
}

// ---------------- Fused: logits -> local softmax partials -> ctx partials
// 512 threads/block: tk = t&127 (token), q = t>>7 (h-quarter of 192 cols,
// wave-pair-uniform). HC2=16 staging keeps LDS at 34.8 KB -> 4 blocks/CU
// * 8 waves = 32 waves/CU (100% occupancy; needs VGPR<=64, footprint ~55).
// Grid stays 1024 so stats/ctxp layouts are unchanged.
__global__ __launch_bounds__(512, 8) void k_fused(const float* __restrict__ X,
                                                  const float* __restrict__ qk,
                                                  const float* __restrict__ qb,
                                                  float* __restrict__ stats,
                                                  float* __restrict__ ctxp) {
  __shared__ float smem[4 * SC * 17];     // 34816 B; reused post-passA
  const int t = threadIdx.x;
  const int chunk = blockIdx.x, b = blockIdx.y;
  const int tk = t & (SC - 1);
  const int q  = __builtin_amdgcn_readfirstlane(t >> 7);   // quarter, wave-uniform
  const float* Xb = X + ((size_t)(b * SS + chunk * SC)) * HID;

  // Staging: stage = 128 rows x 4 quarters x 16 cols = 32 KB. Thread handles
  // float4 idx j = t + m*512: c4 = j&3, row = (j>>2)&127, qq = j>>9.
  // Global: 64-B contiguous per row-quad -> coalesced 64-B segments.
  float4 r[4];
  #pragma unroll
  for (int m = 0; m < 4; ++m) {
    int j = t + m * 512;
    int c4 = j & 3, row = (j >> 2) & (SC - 1), qq = j >> 9;
    r[m] = *(const float4*)(Xb + (size_t)row * HID + qq * DIMD + c4 * 4);
  }

  float acc[NSIG];
  #pragma unroll
  for (int n = 0; n < NSIG; ++n) acc[n] = (q == 0) ? qb[n] : 0.f;

  for (int c = 0; c < NST; ++c) {         // 12 stages per quarter
    __syncthreads();                      // readers of stage c-1 done
    #pragma unroll
    for (int m = 0; m < 4; ++m) {         // regs -> LDS (b32, stride-17 rows)
      int j = t + m * 512;
      int c4 = j & 3, row = (j >> 2) & (SC - 1), qq = j >> 9;
      float* dst = smem + (qq * SC + row) * 17 + c4 * 4;
      dst[0] = r[m].x; dst[1] = r[m].y; dst[2] = r[m].z; dst[3] = r[m].w;
    }
    __syncthreads();                      // stage c visible
    if (c + 1 < NST) {                    // prefetch stage c+1 into regs
      #pragma unroll
      for (int m = 0; m < 4; ++m) {
        int j = t + m * 512;
        int c4 = j & 3, row = (j >> 2) & (SC - 1), qq = j >> 9;
        r[m] = *(const float4*)(Xb + (size_t)row * HID + qq * DIMD + (c + 1) * HC2 + c4 * 4);
      }
    }
    const float* xrow = smem + (q * SC + tk) * 17;   // stride-17: 2 lanes/bank = free
    float x[HC2];
    #pragma unroll
    for (int j = 0; j < HC2; ++j) x[j] = xrow[j];
    const float* Qc = qk + q * DIMD + c * HC2;       // wave-uniform -> s_load
    #pragma unroll
    for (int n = 0; n < NSIG; ++n) {
      const float* Qn = Qc + (size_t)n * HID;
      float s = 0.f;
      #pragma unroll
      for (int j = 0; j < HC2; ++j) s = fmaf(x[j], Qn[j], s);
      acc[n] += s;
    }
  }

  // ---- combine 4 quarters + block-local softmax partials (LDS region reuse)
  __syncthreads();                        // pass-A LDS reads done
  float* comb = smem;                     // [3][15][128] quarter partials
  float* redM = smem + 3 * NSIG * SC;     // [15][2]
  float* redL = redM + NSIG * 2;
  float* redP = redL + NSIG * 2;
  float* wS   = smem + 3 * NSIG * SC + 96; // [16][128]; row 15 zero pad
  const int wv = __builtin_amdgcn_readfirstlane((t >> 6) & 1);

  if (q != 0) {
    #pragma unroll
    for (int n = 0; n < NSIG; ++n) comb[((q - 1) * NSIG + n) * SC + tk] = acc[n];
  }
  if (t >= 384) wS[NSIG * SC + (t - 384)] = 0.f;   // zero pad row for pass B
  __syncthreads();
  if (q == 0) {                            // waves 0-1 own the softmax
    #pragma unroll
    for (int n = 0; n < NSIG; ++n) {
      acc[n] += comb[n * SC + tk] + comb[(NSIG + n) * SC + tk] + comb[(2 * NSIG + n) * SC + tk];
      float v = acc[n];
      #pragma unroll
      for (int o = 32; o > 0; o >>= 1) v = fmaxf(v, __shfl_xor(v, o, 64));
      if ((t & 63) == 0) redM[n * 2 + wv] = v;
    }
  }
  __syncthreads();
  if (q == 0) {
    #pragma unroll
    for (int n = 0; n < NSIG; ++n) {
      float m = fmaxf(redM[n * 2], redM[n * 2 + 1]);
      float e = expf(acc[n] - m);
      wS[n * SC + tk] = e;
      float l = e, pa = e * acc[n];
      #pragma unroll
      for (int o = 32; o > 0; o >>= 1) { l += __shfl_xor(l, o, 64); pa += __shfl_xor(pa, o, 64); }
      if ((t & 63) == 0) { redL[n * 2 + wv] = l; redP[n * 2 + wv] = pa; }
    }
  }
  __syncthreads();
  if (t < NSIG) {
    float m  = fmaxf(redM[t * 2], redM[t * 2 + 1]);
    float l  = redL[t * 2] + redL[t * 2 + 1];
    float pa = redP[t * 2] + redP[t * 2 + 1];
    float* st = stats + ((size_t)((b * NCHUNK + chunk) * NSIG + t)) * 3;
    st[0] = m; st[1] = l; st[2] = pa;
  }

  // ---- Pass B: unnormalized ctx partials. Thread owns cols {cc,+256,+512}
  // and a signal-half (nh): 8 signals each (nh=1 computes dummy n=15 against
  // the zeroed wS row; store predicated). All indexing compile-time.
  const int cc = t & 255;
  const int nh = __builtin_amdgcn_readfirstlane(t >> 8);
  const int n0 = nh * 8;
  float accB[24];
  #pragma unroll
  for (int i = 0; i < 24; ++i) accB[i] = 0.f;
  const float* Xc = Xb + cc;
  for (int s = 0; s < SC; s += 4) {
    float x[12];
    #pragma unroll
    for (int j = 0; j < 4; ++j)
      #pragma unroll
      for (int k = 0; k < 3; ++k)
        x[j * 3 + k] = Xc[(size_t)(s + j) * HID + k * 256];   // coalesced, L2-warm
    #pragma unroll
    for (int i = 0; i < 8; ++i) {
      float4 w4 = *(const float4*)(wS + (n0 + i) * SC + s);   // broadcast b128
      float wa[4] = {w4.x, w4.y, w4.z, w4.w};
      #pragma unroll
      for (int j = 0; j < 4; ++j)
        #pragma unroll
        for (int k = 0; k < 3; ++k)
          accB[i * 3 + k] = fmaf(wa[j], x[j * 3 + k], accB[i * 3 + k]);
    }
  }
  float* dst = ctxp + ((size_t)((b * NCHUNK + chunk) * NSIG)) * HID + cc;
  #pragma unroll
  for (int i = 0; i < 8; ++i)
    if (n0 + i < NSIG)                                        // wave-uniform
      #pragma unroll
      for (int k = 0; k < 3; ++k)
        dst[(size_t)(n0 + i) * HID + k * 256] = accB[i * 3 + k];  // coalesced
}

// ---------------- Final: combine partials, entropy/strength, ctx·Wv, gelu MLP
__global__ __launch_bounds__(256) void k_final(const float* __restrict__ stats,
                                               const float* __restrict__ ctxp,
                                               const float* __restrict__ Wv,
                                               const float* __restrict__ bv,
                                               const float* __restrict__ nullemb,
                                               const float* __restrict__ W1,
                                               const float* __restrict__ b1,
                                               const float* __restrict__ W2,
                                               const float* __restrict__ b2,
                                               float* __restrict__ out) {
  const int blk = blockIdx.x;                  // 0..479
  const int b = blk / NSIG, n = blk - b * NSIG;
  const int t = threadIdx.x;
  __shared__ float alpha[NCHUNK];
  __shared__ float ctx[HID];
  __shared__ float se[DIMD];

  if (t == 0) {
    float mc[NCHUNK], lc[NCHUNK], pc[NCHUNK];
    float m = -1e30f;
    #pragma unroll
    for (int c = 0; c < NCHUNK; ++c) {
      const float* st = stats + ((size_t)((b * NCHUNK + c) * NSIG + n)) * 3;
      mc[c] = st[0]; lc[c] = st[1]; pc[c] = st[2];
      m = fmaxf(m, mc[c]);
    }
    float L = 0.f, PA = 0.f;
    #pragma unroll
    for (int c = 0; c < NCHUNK; ++c) {
      float scl = expf(mc[c] - m);
      L = fmaf(scl, lc[c], L); PA = fmaf(scl, pc[c], PA);
    }
    #pragma unroll
    for (int c = 0; c < NCHUNK; ++c) alpha[c] = expf(mc[c] - m) / L;
    float entropy = m + logf(L) - PA / L;
    out[b * (2 * NSIG) + NSIG + n] = 1.f - entropy / LOG_S;
  }
  __syncthreads();

  #pragma unroll
  for (int k = 0; k < 3; ++k) {
    int h = t + k * 256;
    float s0 = 0.f, s1 = 0.f;                 // 2 chains: break FMA dependence
    #pragma unroll 8
    for (int c = 0; c < NCHUNK; c += 2) {
      s0 = fmaf(alpha[c],     ctxp[((size_t)((b * NCHUNK + c)     * NSIG + n)) * HID + h], s0);
      s1 = fmaf(alpha[c + 1], ctxp[((size_t)((b * NCHUNK + c + 1) * NSIG + n)) * HID + h], s1);
    }
    ctx[h] = s0 + s1;
  }
  __syncthreads();

  if (t < DIMD) {
    float s0 = 0.f, s1 = 0.f, s2 = 0.f, s3 = 0.f;   // 4 chains over 768
    #pragma unroll 2
    for (int h = 0; h < HID; h += 4) {
      s0 = fmaf(ctx[h],     Wv[(size_t)h       * DIMD + t], s0);
      s1 = fmaf(ctx[h + 1], Wv[(size_t)(h + 1) * DIMD + t], s1);
      s2 = fmaf(ctx[h + 2], Wv[(size_t)(h + 2) * DIMD + t], s2);
      s3 = fmaf(ctx[h + 3], Wv[(size_t)(h + 3) * DIMD + t], s3);
    }
    se[t] = bv[t] + ((s0 + s1) + (s2 + s3));
  }
  __syncthreads();

  if (t < 64) {
    float s0 = b1[t], s1 = 0.f, s2 = 0.f, s3 = 0.f;
    const float* nrow = nullemb + (size_t)n * HID;
    #pragma unroll 4
    for (int i = 0; i < DIMD; i += 2) {
      s0 = fmaf(se[i],     W1[(size_t)i       * 64 + t], s0);
      s1 = fmaf(se[i + 1], W1[(size_t)(i + 1) * 64 + t], s1);
    }
    #pragma unroll 4
    for (int i = 0; i < DIMD; i += 2) {
      s2 = fmaf(nrow[i],     W1[(size_t)(DIMD + i)     * 64 + t], s2);
      s3 = fmaf(nrow[i + 1], W1[(size_t)(DIMD + i + 1) * 64 + t], s3);
    }
    float s = (s0 + s1) + (s2 + s3);
    float g = 0.5f * s * (1.f + erff(s * 0.70710678118654752f));  // exact gelu
    float val = g * W2[t];
    #pragma unroll
    for (int o = 32; o > 0; o >>= 1) val += __shfl_down(val, o, 64);
    if (t == 0) out[b * (2 * NSIG) + n] = val + b2[0];
  }
}

extern "C" void kernel_launch(void* const* d_in, const int* in_sizes, int n_in,
                              void* d_out, int out_size, void* d_ws, size_t ws_size,
                              hipStream_t stream) {
  const float* X   = (const float*)d_in[0];
  const float* Wk  = (const float*)d_in[1];
  const float* bk  = (const float*)d_in[2];
  const float* Wv  = (const float*)d_in[3];
  const float* bv  = (const float*)d_in[4];
  const float* q   = (const float*)d_in[5];
  const float* nul = (const float*)d_in[6];
  const float* W1  = (const float*)d_in[7];
  const float* b1  = (const float*)d_in[8];
  const float* W2  = (const float*)d_in[9];
  const float* b2  = (const float*)d_in[10];
  float* out = (float*)d_out;
  float* ws  = (float*)d_ws;    // ~48 MB used

  hipLaunchKernelGGL(k_qk, dim3(45), dim3(256), 0, stream, q, Wk, bk, ws);
  hipLaunchKernelGGL(k_fused, dim3(NCHUNK, BB), dim3(512), 0, stream,
                     X, ws + WS_QK, ws + WS_QB, ws + WS_ST, ws + WS_CTXP);
  hipLaunchKernelGGL(k_final, dim3(BB * NSIG), dim3(256), 0, stream,
                     ws + WS_ST, ws + WS_CTXP, Wv, bv, nul, W1, b1, W2, b2, out);
}

// Round 3
// 712.811 us; speedup vs baseline: 1.1514x; 1.0326x over previous
//
#include <hip/hip_runtime.h>
#include <math.h>

// Problem constants
#define HID   768
#define DIMD  192
#define NSIG  15
#define BB    32
#define SS    4096
#define SC    128                 // tokens per fused block
#define NCHUNK (SS / SC)          // 32
#define CSTG  64                  // globally-contiguous cols staged per stage
#define NST   (HID / CSTG)        // 12 stage iterations
#define HC2   16                  // cols processed per wave-group per stage
#define LDSW  65                  // LDS row stride (floats): 2-way = free
#define INV_SCALE 0.07216878364870322f   // 1/sqrt(192)
#define LOG_S     8.31776616671934f      // ln(4096)

// Workspace layout (floats) — unchanged
#define WS_QK   ((size_t)0)                      // [15][768] scaled Q
#define WS_QB   (WS_QK + NSIG * HID)             // [15] scaled bias dot
#define WS_ST   (WS_QB + 16)                     // [B][32][15][3] m,l,pa partials
#define WS_CTXP (WS_ST + (size_t)BB * NCHUNK * NSIG * 3)  // [B][32][15][768]

// ---------------- Kernel A: Qk[n][h] = (q[n,:]·Wk[h,:])/sqrt(d), qb[n] = (q[n]·bk)/sqrt(d)
__global__ __launch_bounds__(256) void k_qk(const float* __restrict__ q,
                                            const float* __restrict__ Wk,
                                            const float* __restrict__ bk,
                                            float* __restrict__ ws) {
  int idx = blockIdx.x * 256 + threadIdx.x;
  if (idx < NSIG * HID) {
    int n = idx / HID, h = idx - n * HID;
    const float* qr = q + n * DIMD;
    const float* wr = Wk + h * DIMD;
    float s = 0.f;
    #pragma unroll 4
    for (int d = 0; d < DIMD; ++d) s = fmaf(qr[d], wr[d], s);
    ws[WS_QK + (size_t)n * HID + h] = s * INV_SCALE;
  }
  if (idx < NSIG) {
    const float* qr = q + idx * DIMD;
    float s = 0.f;
    for (int d = 0; d < DIMD; ++d) s = fmaf(qr[d], bk[d], s);
    ws[WS_QB + idx] = s * INV_SCALE;
  }
}

// ---------------- Fused: logits -> local softmax partials -> ctx partials
// 512 threads: tk = t&127 (token), g = t>>7 (col-group, wave-pair-uniform).
// Stage c holds the CONTIGUOUS cols [c*64, c*64+64) of all 128 rows, so every
// global segment is 256B (4 rows x 256B per wave-load, fully coalesced).
// Group g computes cols c*64+g*16..+16 each stage; the 4 group partials are
// summed at the combine step (disjoint col subsets -> same total dot).
// LDS [128][65] = 33.3KB -> 4 blocks/CU * 8 waves = 32 waves/CU.
__global__ __launch_bounds__(512, 8) void k_fused(const float* __restrict__ X,
                                                  const float* __restrict__ qk,
                                                  const float* __restrict__ qb,
                                                  float* __restrict__ stats,
                                                  float* __restrict__ ctxp) {
  __shared__ float smem[SC * LDSW];       // 33280 B; reused post-passA
  const int t = threadIdx.x;
  const int chunk = blockIdx.x, b = blockIdx.y;
  const int tk = t & (SC - 1);
  const int g  = __builtin_amdgcn_readfirstlane(t >> 7);   // col-group, wave-uniform
  const float* Xb = X + ((size_t)(b * SS + chunk * SC)) * HID;

  // Staging map: idx = t + m*512 in [0,2048): c4 = idx&15 (float4 within the
  // 64-col slab), row = idx>>4. Global addr = row*3KB + c*256B + c4*16B.
  float4 r[4];
  #pragma unroll
  for (int m = 0; m < 4; ++m) {
    int idx = t + m * 512;
    int c4 = idx & 15, row = idx >> 4;
    r[m] = *(const float4*)(Xb + (size_t)row * HID + c4 * 4);
  }

  float acc[NSIG];
  #pragma unroll
  for (int n = 0; n < NSIG; ++n) acc[n] = (g == 0) ? qb[n] : 0.f;

  for (int c = 0; c < NST; ++c) {         // 12 stages
    __syncthreads();                      // readers of stage c-1 done
    #pragma unroll
    for (int m = 0; m < 4; ++m) {         // regs -> LDS (b32, stride-65 rows)
      int idx = t + m * 512;
      int c4 = idx & 15, row = idx >> 4;
      float* dst = smem + row * LDSW + c4 * 4;
      dst[0] = r[m].x; dst[1] = r[m].y; dst[2] = r[m].z; dst[3] = r[m].w;
    }
    __syncthreads();                      // stage c visible
    if (c + 1 < NST) {                    // prefetch stage c+1 into regs
      #pragma unroll
      for (int m = 0; m < 4; ++m) {
        int idx = t + m * 512;
        int c4 = idx & 15, row = idx >> 4;
        r[m] = *(const float4*)(Xb + (size_t)row * HID + (c + 1) * CSTG + c4 * 4);
      }
    }
    const float* xrow = smem + tk * LDSW + g * HC2;  // (tk+16g+j)%32: 2/bank = free
    float x[HC2];
    #pragma unroll
    for (int j = 0; j < HC2; ++j) x[j] = xrow[j];
    const float* Qc = qk + c * CSTG + g * HC2;       // wave-uniform -> s_load
    #pragma unroll
    for (int n = 0; n < NSIG; ++n) {
      const float* Qn = Qc + (size_t)n * HID;
      float s = 0.f;
      #pragma unroll
      for (int j = 0; j < HC2; ++j) s = fmaf(x[j], Qn[j], s);
      acc[n] += s;
    }
  }

  // ---- combine 4 col-groups + block-local softmax partials (LDS reuse)
  __syncthreads();                        // pass-A LDS reads done
  float* comb = smem;                     // [3][15][128] group partials
  float* redM = smem + 3 * NSIG * SC;     // [15][2]
  float* redL = redM + NSIG * 2;
  float* redP = redL + NSIG * 2;
  float* wS   = smem + 3 * NSIG * SC + 96; // [16][128]; row 15 zero pad
  const int wv = __builtin_amdgcn_readfirstlane((t >> 6) & 1);

  if (g != 0) {
    #pragma unroll
    for (int n = 0; n < NSIG; ++n) comb[((g - 1) * NSIG + n) * SC + tk] = acc[n];
  }
  if (t >= 384) wS[NSIG * SC + (t - 384)] = 0.f;   // zero pad row for pass B
  __syncthreads();
  if (g == 0) {                            // waves 0-1 own the softmax
    #pragma unroll
    for (int n = 0; n < NSIG; ++n) {
      acc[n] += comb[n * SC + tk] + comb[(NSIG + n) * SC + tk] + comb[(2 * NSIG + n) * SC + tk];
      float v = acc[n];
      #pragma unroll
      for (int o = 32; o > 0; o >>= 1) v = fmaxf(v, __shfl_xor(v, o, 64));
      if ((t & 63) == 0) redM[n * 2 + wv] = v;
    }
  }
  __syncthreads();
  if (g == 0) {
    #pragma unroll
    for (int n = 0; n < NSIG; ++n) {
      float m = fmaxf(redM[n * 2], redM[n * 2 + 1]);
      float e = expf(acc[n] - m);
      wS[n * SC + tk] = e;
      float l = e, pa = e * acc[n];
      #pragma unroll
      for (int o = 32; o > 0; o >>= 1) { l += __shfl_xor(l, o, 64); pa += __shfl_xor(pa, o, 64); }
      if ((t & 63) == 0) { redL[n * 2 + wv] = l; redP[n * 2 + wv] = pa; }
    }
  }
  __syncthreads();
  if (t < NSIG) {
    float m  = fmaxf(redM[t * 2], redM[t * 2 + 1]);
    float l  = redL[t * 2] + redL[t * 2 + 1];
    float pa = redP[t * 2] + redP[t * 2 + 1];
    float* st = stats + ((size_t)((b * NCHUNK + chunk) * NSIG + t)) * 3;
    st[0] = m; st[1] = l; st[2] = pa;
  }

  // ---- Pass B: unnormalized ctx partials. Thread owns cols {cc,+256,+512}
  // and a signal-half (nh): 8 signals each (nh=1 computes dummy n=15 against
  // the zeroed wS row; store predicated). All indexing compile-time.
  const int cc = t & 255;
  const int nh = __builtin_amdgcn_readfirstlane(t >> 8);
  const int n0 = nh * 8;
  float accB[24];
  #pragma unroll
  for (int i = 0; i < 24; ++i) accB[i] = 0.f;
  const float* Xc = Xb + cc;
  for (int s = 0; s < SC; s += 4) {
    float x[12];
    #pragma unroll
    for (int j = 0; j < 4; ++j)
      #pragma unroll
      for (int k = 0; k < 3; ++k)
        x[j * 3 + k] = Xc[(size_t)(s + j) * HID + k * 256];   // coalesced, L2/L3-warm
    #pragma unroll
    for (int i = 0; i < 8; ++i) {
      float4 w4 = *(const float4*)(wS + (n0 + i) * SC + s);   // broadcast b128
      float wa[4] = {w4.x, w4.y, w4.z, w4.w};
      #pragma unroll
      for (int j = 0; j < 4; ++j)
        #pragma unroll
        for (int k = 0; k < 3; ++k)
          accB[i * 3 + k] = fmaf(wa[j], x[j * 3 + k], accB[i * 3 + k]);
    }
  }
  float* dst = ctxp + ((size_t)((b * NCHUNK + chunk) * NSIG)) * HID + cc;
  #pragma unroll
  for (int i = 0; i < 8; ++i)
    if (n0 + i < NSIG)                                        // wave-uniform
      #pragma unroll
      for (int k = 0; k < 3; ++k)
        dst[(size_t)(n0 + i) * HID + k * 256] = accB[i * 3 + k];  // coalesced
}

// ---------------- Final: combine partials, entropy/strength, ctx·Wv, gelu MLP
__global__ __launch_bounds__(256) void k_final(const float* __restrict__ stats,
                                               const float* __restrict__ ctxp,
                                               const float* __restrict__ Wv,
                                               const float* __restrict__ bv,
                                               const float* __restrict__ nullemb,
                                               const float* __restrict__ W1,
                                               const float* __restrict__ b1,
                                               const float* __restrict__ W2,
                                               const float* __restrict__ b2,
                                               float* __restrict__ out) {
  const int blk = blockIdx.x;                  // 0..479
  const int b = blk / NSIG, n = blk - b * NSIG;
  const int t = threadIdx.x;
  __shared__ float alpha[NCHUNK];
  __shared__ float ctx[HID];
  __shared__ float se[DIMD];

  if (t < NCHUNK) {                            // 32 lanes, parallel alpha
    const float* st = stats + ((size_t)((b * NCHUNK + t) * NSIG + n)) * 3;
    float mc = st[0], lc = st[1], pc = st[2];
    float m = mc;
    #pragma unroll
    for (int o = 16; o > 0; o >>= 1) m = fmaxf(m, __shfl_xor(m, o, 64));
    float scl = expf(mc - m);
    float L = scl * lc, PA = scl * pc;
    #pragma unroll
    for (int o = 16; o > 0; o >>= 1) { L += __shfl_xor(L, o, 64); PA += __shfl_xor(PA, o, 64); }
    alpha[t] = scl / L;
    if (t == 0) {
      float entropy = m + logf(L) - PA / L;
      out[b * (2 * NSIG) + NSIG + n] = 1.f - entropy / LOG_S;
    }
  }
  __syncthreads();

  #pragma unroll
  for (int k = 0; k < 3; ++k) {
    int h = t + k * 256;
    float s0 = 0.f, s1 = 0.f;                 // 2 chains: break FMA dependence
    #pragma unroll 8
    for (int c = 0; c < NCHUNK; c += 2) {
      s0 = fmaf(alpha[c],     ctxp[((size_t)((b * NCHUNK + c)     * NSIG + n)) * HID + h], s0);
      s1 = fmaf(alpha[c + 1], ctxp[((size_t)((b * NCHUNK + c + 1) * NSIG + n)) * HID + h], s1);
    }
    ctx[h] = s0 + s1;
  }
  __syncthreads();

  if (t < DIMD) {
    float s0 = 0.f, s1 = 0.f, s2 = 0.f, s3 = 0.f;   // 4 chains over 768
    #pragma unroll 2
    for (int h = 0; h < HID; h += 4) {
      s0 = fmaf(ctx[h],     Wv[(size_t)h       * DIMD + t], s0);
      s1 = fmaf(ctx[h + 1], Wv[(size_t)(h + 1) * DIMD + t], s1);
      s2 = fmaf(ctx[h + 2], Wv[(size_t)(h + 2) * DIMD + t], s2);
      s3 = fmaf(ctx[h + 3], Wv[(size_t)(h + 3) * DIMD + t], s3);
    }
    se[t] = bv[t] + ((s0 + s1) + (s2 + s3));
  }
  __syncthreads();

  if (t < 64) {
    float s0 = b1[t], s1 = 0.f, s2 = 0.f, s3 = 0.f;
    const float* nrow = nullemb + (size_t)n * HID;
    #pragma unroll 4
    for (int i = 0; i < DIMD; i += 2) {
      s0 = fmaf(se[i],     W1[(size_t)i       * 64 + t], s0);
      s1 = fmaf(se[i + 1], W1[(size_t)(i + 1) * 64 + t], s1);
    }
    #pragma unroll 4
    for (int i = 0; i < DIMD; i += 2) {
      s2 = fmaf(nrow[i],     W1[(size_t)(DIMD + i)     * 64 + t], s2);
      s3 = fmaf(nrow[i + 1], W1[(size_t)(DIMD + i + 1) * 64 + t], s3);
    }
    float s = (s0 + s1) + (s2 + s3);
    float g = 0.5f * s * (1.f + erff(s * 0.70710678118654752f));  // exact gelu
    float val = g * W2[t];
    #pragma unroll
    for (int o = 32; o > 0; o >>= 1) val += __shfl_down(val, o, 64);
    if (t == 0) out[b * (2 * NSIG) + n] = val + b2[0];
  }
}

extern "C" void kernel_launch(void* const* d_in, const int* in_sizes, int n_in,
                              void* d_out, int out_size, void* d_ws, size_t ws_size,
                              hipStream_t stream) {
  const float* X   = (const float*)d_in[0];
  const float* Wk  = (const float*)d_in[1];
  const float* bk  = (const float*)d_in[2];
  const float* Wv  = (const float*)d_in[3];
  const float* bv  = (const float*)d_in[4];
  const float* q   = (const float*)d_in[5];
  const float* nul = (const float*)d_in[6];
  const float* W1  = (const float*)d_in[7];
  const float* b1  = (const float*)d_in[8];
  const float* W2  = (const float*)d_in[9];
  const float* b2  = (const float*)d_in[10];
  float* out = (float*)d_out;
  float* ws  = (float*)d_ws;    // ~48 MB used

  hipLaunchKernelGGL(k_qk, dim3(45), dim3(256), 0, stream, q, Wk, bk, ws);
  hipLaunchKernelGGL(k_fused, dim3(NCHUNK, BB), dim3(512), 0, stream,
                     X, ws + WS_QK, ws + WS_QB, ws + WS_ST, ws + WS_CTXP);
  hipLaunchKernelGGL(k_final, dim3(BB * NSIG), dim3(256), 0, stream,
                     ws + WS_ST, ws + WS_CTXP, Wv, bv, nul, W1, b1, W2, b2, out);
}

// Round 4
// 703.291 us; speedup vs baseline: 1.1670x; 1.0135x over previous
//
#include <hip/hip_runtime.h>
#include <math.h>

// Problem constants
#define HID   768
#define DIMD  192
#define NSIG  15
#define BB    32
#define SS    4096
#define SC    128                 // tokens per fused block
#define NCHUNK (SS / SC)          // 32
#define CSTG  64                  // globally-contiguous cols staged per stage
#define NST   (HID / CSTG)        // 12 stage iterations
#define HC2   16                  // cols processed per wave-group per stage
#define LDSW  65                  // LDS row stride (floats): 2-way = free
#define INV_SCALE 0.07216878364870322f   // 1/sqrt(192)
#define LOG_S     8.31776616671934f      // ln(4096)

// Workspace layout (floats) — unchanged
#define WS_QK   ((size_t)0)                      // [15][768] scaled Q
#define WS_QB   (WS_QK + NSIG * HID)             // [15] scaled bias dot
#define WS_ST   (WS_QB + 16)                     // [B][32][15][3] m,l,pa partials
#define WS_CTXP (WS_ST + (size_t)BB * NCHUNK * NSIG * 3)  // [B][32][15][768]

// ---------------- Kernel A (v2): wave-per-h. Wave w of block bl owns output
// row h = bl*8+w. Lanes load Wk[h][lane,+64,+128] -- three fully-coalesced
// 256B wave-loads (vs 64-line-amplified stride-768B loads in v1). 15 dots
// against L1-resident q, butterfly reduce, single 15-lane scattered store.
__global__ __launch_bounds__(512) void k_qk(const float* __restrict__ q,
                                            const float* __restrict__ Wk,
                                            const float* __restrict__ bk,
                                            float* __restrict__ ws) {
  const int t = threadIdx.x;
  const int lane = t & 63;
  const int w = __builtin_amdgcn_readfirstlane(t >> 6);
  const int h = blockIdx.x * 8 + w;                 // 0..767
  const float* wr = Wk + (size_t)h * DIMD;
  const float w0 = wr[lane], w1 = wr[64 + lane], w2 = wr[128 + lane];
  float val = 0.f;
  #pragma unroll
  for (int n = 0; n < NSIG; ++n) {
    const float* qn = q + n * DIMD;
    float p = qn[lane] * w0 + qn[64 + lane] * w1 + qn[128 + lane] * w2;
    #pragma unroll
    for (int o = 32; o > 0; o >>= 1) p += __shfl_xor(p, o, 64);
    if (lane == n) val = p;                         // lane n keeps dot n
  }
  if (lane < NSIG) ws[WS_QK + (size_t)lane * HID + h] = val * INV_SCALE;

  if (blockIdx.x == 0) {                            // qb: n = w and w+8
    #pragma unroll
    for (int r2 = 0; r2 < 2; ++r2) {
      int n = w + r2 * 8;
      if (n < NSIG) {
        const float* qn = q + n * DIMD;
        float p = qn[lane] * bk[lane] + qn[64 + lane] * bk[64 + lane]
                + qn[128 + lane] * bk[128 + lane];
        #pragma unroll
        for (int o = 32; o > 0; o >>= 1) p += __shfl_xor(p, o, 64);
        if (lane == 0) ws[WS_QB + n] = p * INV_SCALE;
      }
    }
  }
}

// ---------------- Fused: logits -> local softmax partials -> ctx partials
// (unchanged from round 3 -- single-variable round)
__global__ __launch_bounds__(512, 8) void k_fused(const float* __restrict__ X,
                                                  const float* __restrict__ qk,
                                                  const float* __restrict__ qb,
                                                  float* __restrict__ stats,
                                                  float* __restrict__ ctxp) {
  __shared__ float smem[SC * LDSW];       // 33280 B; reused post-passA
  const int t = threadIdx.x;
  const int chunk = blockIdx.x, b = blockIdx.y;
  const int tk = t & (SC - 1);
  const int g  = __builtin_amdgcn_readfirstlane(t >> 7);   // col-group, wave-uniform
  const float* Xb = X + ((size_t)(b * SS + chunk * SC)) * HID;

  float4 r[4];
  #pragma unroll
  for (int m = 0; m < 4; ++m) {
    int idx = t + m * 512;
    int c4 = idx & 15, row = idx >> 4;
    r[m] = *(const float4*)(Xb + (size_t)row * HID + c4 * 4);
  }

  float acc[NSIG];
  #pragma unroll
  for (int n = 0; n < NSIG; ++n) acc[n] = (g == 0) ? qb[n] : 0.f;

  for (int c = 0; c < NST; ++c) {         // 12 stages
    __syncthreads();                      // readers of stage c-1 done
    #pragma unroll
    for (int m = 0; m < 4; ++m) {         // regs -> LDS (b32, stride-65 rows)
      int idx = t + m * 512;
      int c4 = idx & 15, row = idx >> 4;
      float* dst = smem + row * LDSW + c4 * 4;
      dst[0] = r[m].x; dst[1] = r[m].y; dst[2] = r[m].z; dst[3] = r[m].w;
    }
    __syncthreads();                      // stage c visible
    if (c + 1 < NST) {                    // prefetch stage c+1 into regs
      #pragma unroll
      for (int m = 0; m < 4; ++m) {
        int idx = t + m * 512;
        int c4 = idx & 15, row = idx >> 4;
        r[m] = *(const float4*)(Xb + (size_t)row * HID + (c + 1) * CSTG + c4 * 4);
      }
    }
    const float* xrow = smem + tk * LDSW + g * HC2;  // 2 lanes/bank = free
    float x[HC2];
    #pragma unroll
    for (int j = 0; j < HC2; ++j) x[j] = xrow[j];
    const float* Qc = qk + c * CSTG + g * HC2;       // wave-uniform -> s_load
    #pragma unroll
    for (int n = 0; n < NSIG; ++n) {
      const float* Qn = Qc + (size_t)n * HID;
      float s = 0.f;
      #pragma unroll
      for (int j = 0; j < HC2; ++j) s = fmaf(x[j], Qn[j], s);
      acc[n] += s;
    }
  }

  // ---- combine 4 col-groups + block-local softmax partials (LDS reuse)
  __syncthreads();                        // pass-A LDS reads done
  float* comb = smem;                     // [3][15][128] group partials
  float* redM = smem + 3 * NSIG * SC;     // [15][2]
  float* redL = redM + NSIG * 2;
  float* redP = redL + NSIG * 2;
  float* wS   = smem + 3 * NSIG * SC + 96; // [16][128]; row 15 zero pad
  const int wv = __builtin_amdgcn_readfirstlane((t >> 6) & 1);

  if (g != 0) {
    #pragma unroll
    for (int n = 0; n < NSIG; ++n) comb[((g - 1) * NSIG + n) * SC + tk] = acc[n];
  }
  if (t >= 384) wS[NSIG * SC + (t - 384)] = 0.f;   // zero pad row for pass B
  __syncthreads();
  if (g == 0) {                            // waves 0-1 own the softmax
    #pragma unroll
    for (int n = 0; n < NSIG; ++n) {
      acc[n] += comb[n * SC + tk] + comb[(NSIG + n) * SC + tk] + comb[(2 * NSIG + n) * SC + tk];
      float v = acc[n];
      #pragma unroll
      for (int o = 32; o > 0; o >>= 1) v = fmaxf(v, __shfl_xor(v, o, 64));
      if ((t & 63) == 0) redM[n * 2 + wv] = v;
    }
  }
  __syncthreads();
  if (g == 0) {
    #pragma unroll
    for (int n = 0; n < NSIG; ++n) {
      float m = fmaxf(redM[n * 2], redM[n * 2 + 1]);
      float e = expf(acc[n] - m);
      wS[n * SC + tk] = e;
      float l = e, pa = e * acc[n];
      #pragma unroll
      for (int o = 32; o > 0; o >>= 1) { l += __shfl_xor(l, o, 64); pa += __shfl_xor(pa, o, 64); }
      if ((t & 63) == 0) { redL[n * 2 + wv] = l; redP[n * 2 + wv] = pa; }
    }
  }
  __syncthreads();
  if (t < NSIG) {
    float m  = fmaxf(redM[t * 2], redM[t * 2 + 1]);
    float l  = redL[t * 2] + redL[t * 2 + 1];
    float pa = redP[t * 2] + redP[t * 2 + 1];
    float* st = stats + ((size_t)((b * NCHUNK + chunk) * NSIG + t)) * 3;
    st[0] = m; st[1] = l; st[2] = pa;
  }

  // ---- Pass B: unnormalized ctx partials.
  const int cc = t & 255;
  const int nh = __builtin_amdgcn_readfirstlane(t >> 8);
  const int n0 = nh * 8;
  float accB[24];
  #pragma unroll
  for (int i = 0; i < 24; ++i) accB[i] = 0.f;
  const float* Xc = Xb + cc;
  for (int s = 0; s < SC; s += 4) {
    float x[12];
    #pragma unroll
    for (int j = 0; j < 4; ++j)
      #pragma unroll
      for (int k = 0; k < 3; ++k)
        x[j * 3 + k] = Xc[(size_t)(s + j) * HID + k * 256];   // coalesced, L2/L3-warm
    #pragma unroll
    for (int i = 0; i < 8; ++i) {
      float4 w4 = *(const float4*)(wS + (n0 + i) * SC + s);   // broadcast b128
      float wa[4] = {w4.x, w4.y, w4.z, w4.w};
      #pragma unroll
      for (int j = 0; j < 4; ++j)
        #pragma unroll
        for (int k = 0; k < 3; ++k)
          accB[i * 3 + k] = fmaf(wa[j], x[j * 3 + k], accB[i * 3 + k]);
    }
  }
  float* dst = ctxp + ((size_t)((b * NCHUNK + chunk) * NSIG)) * HID + cc;
  #pragma unroll
  for (int i = 0; i < 8; ++i)
    if (n0 + i < NSIG)                                        // wave-uniform
      #pragma unroll
      for (int k = 0; k < 3; ++k)
        dst[(size_t)(n0 + i) * HID + k * 256] = accB[i * 3 + k];  // coalesced
}

// ---------------- Final: combine partials, entropy/strength, ctx·Wv, gelu MLP
// (unchanged from round 3)
__global__ __launch_bounds__(256) void k_final(const float* __restrict__ stats,
                                               const float* __restrict__ ctxp,
                                               const float* __restrict__ Wv,
                                               const float* __restrict__ bv,
                                               const float* __restrict__ nullemb,
                                               const float* __restrict__ W1,
                                               const float* __restrict__ b1,
                                               const float* __restrict__ W2,
                                               const float* __restrict__ b2,
                                               float* __restrict__ out) {
  const int blk = blockIdx.x;                  // 0..479
  const int b = blk / NSIG, n = blk - b * NSIG;
  const int t = threadIdx.x;
  __shared__ float alpha[NCHUNK];
  __shared__ float ctx[HID];
  __shared__ float se[DIMD];

  if (t < NCHUNK) {                            // 32 lanes, parallel alpha
    const float* st = stats + ((size_t)((b * NCHUNK + t) * NSIG + n)) * 3;
    float mc = st[0], lc = st[1], pc = st[2];
    float m = mc;
    #pragma unroll
    for (int o = 16; o > 0; o >>= 1) m = fmaxf(m, __shfl_xor(m, o, 64));
    float scl = expf(mc - m);
    float L = scl * lc, PA = scl * pc;
    #pragma unroll
    for (int o = 16; o > 0; o >>= 1) { L += __shfl_xor(L, o, 64); PA += __shfl_xor(PA, o, 64); }
    alpha[t] = scl / L;
    if (t == 0) {
      float entropy = m + logf(L) - PA / L;
      out[b * (2 * NSIG) + NSIG + n] = 1.f - entropy / LOG_S;
    }
  }
  __syncthreads();

  #pragma unroll
  for (int k = 0; k < 3; ++k) {
    int h = t + k * 256;
    float s0 = 0.f, s1 = 0.f;                 // 2 chains: break FMA dependence
    #pragma unroll 8
    for (int c = 0; c < NCHUNK; c += 2) {
      s0 = fmaf(alpha[c],     ctxp[((size_t)((b * NCHUNK + c)     * NSIG + n)) * HID + h], s0);
      s1 = fmaf(alpha[c + 1], ctxp[((size_t)((b * NCHUNK + c + 1) * NSIG + n)) * HID + h], s1);
    }
    ctx[h] = s0 + s1;
  }
  __syncthreads();

  if (t < DIMD) {
    float s0 = 0.f, s1 = 0.f, s2 = 0.f, s3 = 0.f;   // 4 chains over 768
    #pragma unroll 2
    for (int h = 0; h < HID; h += 4) {
      s0 = fmaf(ctx[h],     Wv[(size_t)h       * DIMD + t], s0);
      s1 = fmaf(ctx[h + 1], Wv[(size_t)(h + 1) * DIMD + t], s1);
      s2 = fmaf(ctx[h + 2], Wv[(size_t)(h + 2) * DIMD + t], s2);
      s3 = fmaf(ctx[h + 3], Wv[(size_t)(h + 3) * DIMD + t], s3);
    }
    se[t] = bv[t] + ((s0 + s1) + (s2 + s3));
  }
  __syncthreads();

  if (t < 64) {
    float s0 = b1[t], s1 = 0.f, s2 = 0.f, s3 = 0.f;
    const float* nrow = nullemb + (size_t)n * HID;
    #pragma unroll 4
    for (int i = 0; i < DIMD; i += 2) {
      s0 = fmaf(se[i],     W1[(size_t)i       * 64 + t], s0);
      s1 = fmaf(se[i + 1], W1[(size_t)(i + 1) * 64 + t], s1);
    }
    #pragma unroll 4
    for (int i = 0; i < DIMD; i += 2) {
      s2 = fmaf(nrow[i],     W1[(size_t)(DIMD + i)     * 64 + t], s2);
      s3 = fmaf(nrow[i + 1], W1[(size_t)(DIMD + i + 1) * 64 + t], s3);
    }
    float s = (s0 + s1) + (s2 + s3);
    float g = 0.5f * s * (1.f + erff(s * 0.70710678118654752f));  // exact gelu
    float val = g * W2[t];
    #pragma unroll
    for (int o = 32; o > 0; o >>= 1) val += __shfl_down(val, o, 64);
    if (t == 0) out[b * (2 * NSIG) + n] = val + b2[0];
  }
}

extern "C" void kernel_launch(void* const* d_in, const int* in_sizes, int n_in,
                              void* d_out, int out_size, void* d_ws, size_t ws_size,
                              hipStream_t stream) {
  const float* X   = (const float*)d_in[0];
  const float* Wk  = (const float*)d_in[1];
  const float* bk  = (const float*)d_in[2];
  const float* Wv  = (const float*)d_in[3];
  const float* bv  = (const float*)d_in[4];
  const float* q   = (const float*)d_in[5];
  const float* nul = (const float*)d_in[6];
  const float* W1  = (const float*)d_in[7];
  const float* b1  = (const float*)d_in[8];
  const float* W2  = (const float*)d_in[9];
  const float* b2  = (const float*)d_in[10];
  float* out = (float*)d_out;
  float* ws  = (float*)d_ws;    // ~48 MB used

  hipLaunchKernelGGL(k_qk, dim3(96), dim3(512), 0, stream, q, Wk, bk, ws);
  hipLaunchKernelGGL(k_fused, dim3(NCHUNK, BB), dim3(512), 0, stream,
                     X, ws + WS_QK, ws + WS_QB, ws + WS_ST, ws + WS_CTXP);
  hipLaunchKernelGGL(k_final, dim3(BB * NSIG), dim3(256), 0, stream,
                     ws + WS_ST, ws + WS_CTXP, Wv, bv, nul, W1, b1, W2, b2, out);
}